// Round 24
// baseline (68.902 us; speedup 1.0000x reference)
//
#include <hip/hip_runtime.h>
#include <hip/hip_bf16.h>

#define HH 192
#define WW 192
#define HOUT 190
#define NCH 64
#define W2_N (64 * 9 * 64)
#define XG_OFF 131072   // byte offset of xg in d_ws (w2 occupies first 73,728 B)

typedef __attribute__((ext_vector_type(8))) short bf16x8;
typedef __attribute__((ext_vector_type(4))) float f32x4;

static __device__ __forceinline__ ushort f2bf(float f) {
    __hip_bfloat16 h = __float2bfloat16(f);   // RNE
    return *reinterpret_cast<ushort*>(&h);
}

// W2[o][tap][c] = sum_t (conn[o*16+t]==c) * w[(o*16+t)*9 + tap], bf16.
__global__ __launch_bounds__(256) void build_w2(const float* __restrict__ w,
                                                const int* __restrict__ conn,
                                                ushort* __restrict__ w2) {
    int idx = blockIdx.x * 256 + threadIdx.x;
    if (idx >= W2_N) return;
    int o = idx / 576, rem = idx - o * 576, tap = rem >> 6, c = rem & 63;
    float s = 0.f;
    #pragma unroll
    for (int t = 0; t < 16; ++t) {
        int k = o * 16 + t;
        if (conn[k] == c) s += w[k * 9 + tap];
    }
    w2[idx] = f2bf(s);
}

// NCHW f32 -> NHWC bf16 transpose-cast: xg[b][r][c][ch] = bf16(x[b][ch][r][c]).
// Block = one (b, row, 64-col segment). Coalesced reads per wave; LDS
// [64 col][68 ch-slots] transpose; 32B-coalesced writes.
__global__ __launch_bounds__(256) void nhwc_cast(const float* __restrict__ x,
                                                 ushort* __restrict__ xg) {
    __shared__ ushort t[64][68];
    const int tid = threadIdx.x;
    const int seg = blockIdx.x % 3;
    const int r   = blockIdx.x / 3;
    const int b   = blockIdx.y;

    const int cc  = tid & 63;
    const int chq = tid >> 6;            // 0..3
    #pragma unroll
    for (int it = 0; it < 16; ++it) {
        const int ch = it * 4 + chq;
        t[cc][ch] = f2bf(x[(((size_t)(b * NCH + ch)) * HH + r) * WW + seg * 64 + cc]);
    }
    __syncthreads();

    const int c = tid >> 2;              // 0..63
    const int q = tid & 3;               // 16-ch chunk
    const ushort* src = &t[c][q * 16];
    ushort* dst = xg + (((size_t)(b * HH + r)) * WW + seg * 64 + c) * NCH + q * 16;
    *(uint4*)(dst)     = *(const uint4*)(src);
    *(uint4*)(dst + 8) = *(const uint4*)(src + 8);
}

// Dense 64->64 3x3 conv via mfma_f32_16x16x32_bf16, operand-swapped
// (A = W2 -> D rows = o-quads, D lanes = contiguous pixel cols).
// R24: NO LDS / NO barrier — A-fragments load directly from NHWC bf16 xg
// (one aligned 16B global load each, L1-resident per block).
__global__ __launch_bounds__(256, 3) void scm_mfma(
    const ushort* __restrict__ xg,
    const ushort* __restrict__ w2,
    const float* __restrict__ bias,
    float* __restrict__ out)
{
    const int tid  = threadIdx.x;
    const int lane = tid & 63;
    const int wv   = tid >> 6;
    const int col  = lane & 15;           // A-frag m (o) / B-frag n (pixel col)
    const int g    = lane >> 4;           // k-subgroup

    // Flattened grid (1152) + bijective XCD swizzle (1152 % 8 == 0).
    const int bid = blockIdx.x;
    const int lid = (bid & 7) * 144 + (bid >> 3);
    const int b      = lid / 288;
    const int tileid = lid % 288;
    const int ti0 = (tileid / 12) * 8;    // 24 row tiles
    const int tj0 = (tileid % 12) * 16;   // 12 col tiles

    // Precomputed element offsets (ushort units) into xg:
    // elem = rowoff[R] + coloff[kw] + s*32, fragment = 8 ushorts at that base.
    // Clamped rows/cols feed only outputs >= 190 (discarded at store).
    int rowoff[10];
    #pragma unroll
    for (int R = 0; R < 10; ++R) {
        int gr = ti0 + R; if (gr > 191) gr = 191;
        rowoff[R] = (b * HH + gr) * (WW * NCH);
    }
    int coloff[3];
    #pragma unroll
    for (int kw = 0; kw < 3; ++kw) {
        int gc = tj0 + col + kw; if (gc > 191) gc = 191;
        coloff[kw] = gc * NCH + g * 8;
    }

    f32x4 acc[8];
    #pragma unroll
    for (int i = 0; i < 8; ++i) acc[i] = (f32x4){0.f, 0.f, 0.f, 0.f};

    const ushort* bp = w2 + (16 * wv + col) * 576 + g * 8;

    #pragma unroll
    for (int s = 0; s < 2; ++s) {
        bf16x8 Bs[9];
        #pragma unroll
        for (int tap = 0; tap < 9; ++tap)
            Bs[tap] = *(const bf16x8*)(bp + tap * 64 + s * 32);
        #pragma unroll
        for (int kw = 0; kw < 3; ++kw) {
            bf16x8 f[10];
            #pragma unroll
            for (int R = 0; R < 10; ++R)
                f[R] = *(const bf16x8*)(xg + rowoff[R] + coloff[kw] + s * 32);
            __builtin_amdgcn_sched_barrier(0);   // loads clustered before MFMAs
            #pragma unroll
            for (int Mt = 0; Mt < 8; ++Mt) {
                acc[Mt] = __builtin_amdgcn_mfma_f32_16x16x32_bf16(Bs[kw],     f[Mt],     acc[Mt], 0, 0, 0);
                acc[Mt] = __builtin_amdgcn_mfma_f32_16x16x32_bf16(Bs[3 + kw], f[Mt + 1], acc[Mt], 0, 0, 0);
                acc[Mt] = __builtin_amdgcn_mfma_f32_16x16x32_bf16(Bs[6 + kw], f[Mt + 2], acc[Mt], 0, 0, 0);
            }
        }
    }

    // ---- epilogue: D col = lane&15 = pixel col (contiguous); D row = o-quad.
    const int pcol = tj0 + col;
    const int obase = 16 * wv + 4 * g;
    float bv[4];
    #pragma unroll
    for (int reg = 0; reg < 4; ++reg) bv[reg] = bias[obase + reg];

    if (pcol < HOUT) {
        #pragma unroll
        for (int Mt = 0; Mt < 8; ++Mt) {
            const int row = ti0 + Mt;
            if (row < HOUT) {
                float* rp = out + ((size_t)(b * NCH + obase) * HOUT + row) * HOUT + pcol;
                #pragma unroll
                for (int reg = 0; reg < 4; ++reg)
                    rp[(size_t)reg * HOUT * HOUT] = acc[Mt][reg] + bv[reg];
            }
        }
    }
}

extern "C" void kernel_launch(void* const* d_in, const int* in_sizes, int n_in,
                              void* d_out, int out_size, void* d_ws, size_t ws_size,
                              hipStream_t stream) {
    const float* x       = (const float*)d_in[0];
    const float* weight  = (const float*)d_in[1];
    const float* bias    = (const float*)d_in[2];
    const int*   conn_in = (const int*)d_in[3];
    // d_in[4] = conn_out (implicit: k -> k/16)

    ushort* w2 = (ushort*)d_ws;                          // 73,728 B
    ushort* xg = (ushort*)((char*)d_ws + XG_OFF);        // 18.9 MB NHWC bf16

    nhwc_cast<<<dim3(3 * HH, 4), dim3(256), 0, stream>>>(x, xg);
    build_w2<<<dim3((W2_N + 255) / 256), dim3(256), 0, stream>>>(weight, conn_in, w2);

    scm_mfma<<<dim3(1152), dim3(256), 0, stream>>>(xg, w2, bias, (float*)d_out);
}

// Round 25
// 45.268 us; speedup vs baseline: 1.5221x; 1.5221x over previous
//
#include <hip/hip_runtime.h>
#include <hip/hip_bf16.h>

#define HH 192
#define WW 192
#define HOUT 190
#define NCH 64
#define W2_N (64 * 9 * 64)
#define XG_OFF 131072   // byte offset of xg in d_ws (w2 occupies first 73,728 B)

typedef __attribute__((ext_vector_type(8))) short bf16x8;
typedef __attribute__((ext_vector_type(4))) float f32x4;

static __device__ __forceinline__ ushort f2bf(float f) {
    __hip_bfloat16 h = __float2bfloat16(f);   // RNE
    return *reinterpret_cast<ushort*>(&h);
}

// W2[o][tap][c] = sum_t (conn[o*16+t]==c) * w[(o*16+t)*9 + tap], bf16.
__global__ __launch_bounds__(256) void build_w2(const float* __restrict__ w,
                                                const int* __restrict__ conn,
                                                ushort* __restrict__ w2) {
    int idx = blockIdx.x * 256 + threadIdx.x;
    if (idx >= W2_N) return;
    int o = idx / 576, rem = idx - o * 576, tap = rem >> 6, c = rem & 63;
    float s = 0.f;
    #pragma unroll
    for (int t = 0; t < 16; ++t) {
        int k = o * 16 + t;
        if (conn[k] == c) s += w[k * 9 + tap];
    }
    w2[idx] = f2bf(s);
}

// NCHW f32 -> K-split NHWC bf16:
//   xg elem offset(b,r,kg,c,k) = (((b*192 + r)*8 + kg)*192 + c)*8 + k
// No LDS / no sync: thread = (kg, col); 8 coalesced scalar loads (lanes =
// consecutive cols -> 128B segments), pack bf16x8, one 16B contiguous write.
__global__ __launch_bounds__(256) void ksplit_cast(const float* __restrict__ x,
                                                   ushort* __restrict__ xg) {
    const int tid = threadIdx.x;
    const int kg  = tid >> 5;            // 0..7
    const int c0  = tid & 31;
    const int r   = blockIdx.x / 6;
    const int seg = blockIdx.x % 6;
    const int b   = blockIdx.y;
    const int col = seg * 32 + c0;

    ushort t[8];
    #pragma unroll
    for (int k = 0; k < 8; ++k)
        t[k] = f2bf(x[((size_t)(b * NCH + kg * 8 + k) * HH + r) * WW + col]);

    uint4 v;
    v.x = (uint)t[0] | ((uint)t[1] << 16);
    v.y = (uint)t[2] | ((uint)t[3] << 16);
    v.z = (uint)t[4] | ((uint)t[5] << 16);
    v.w = (uint)t[6] | ((uint)t[7] << 16);
    ushort* dst = xg + ((((size_t)b * HH + r) * 8 + kg) * WW + col) * 8;
    *(uint4*)dst = v;
}

// Dense 64->64 3x3 conv via mfma_f32_16x16x32_bf16, operand-swapped
// (A = W2 -> D rows = o-quads, D lanes = contiguous pixel cols).
// R25: NO LDS / NO barrier; A-fragments load from K-split xg — each 16-lane
// col-group reads 256B CONTIGUOUS (4 segments/wave-instr vs R24's 16).
__global__ __launch_bounds__(256, 4) void scm_mfma(
    const ushort* __restrict__ xg,
    const ushort* __restrict__ w2,
    const float* __restrict__ bias,
    float* __restrict__ out)
{
    const int tid  = threadIdx.x;
    const int lane = tid & 63;
    const int wv   = tid >> 6;
    const int col  = lane & 15;           // A-frag m (o) / B-frag n (pixel col)
    const int g    = lane >> 4;           // k-subgroup

    // Flattened grid (1152) + bijective XCD swizzle (1152 % 8 == 0).
    const int bid = blockIdx.x;
    const int lid = (bid & 7) * 144 + (bid >> 3);
    const int b      = lid / 288;
    const int tileid = lid % 288;
    const int ti0 = (tileid / 12) * 8;    // 24 row tiles
    const int tj0 = (tileid % 12) * 16;   // 12 col tiles

    // Element-offset pieces (ushort units). Clamped rows/cols feed only
    // outputs >= 190 (discarded at store).
    int rowbase[10];
    #pragma unroll
    for (int R = 0; R < 10; ++R) {
        int gr = ti0 + R; if (gr > 191) gr = 191;
        rowbase[R] = (b * HH + gr) * (8 * WW * 8);
    }
    int coloff[3];
    #pragma unroll
    for (int kw = 0; kw < 3; ++kw) {
        int gc = tj0 + col + kw; if (gc > 191) gc = 191;
        coloff[kw] = gc * 8;
    }

    f32x4 acc[8];
    #pragma unroll
    for (int i = 0; i < 8; ++i) acc[i] = (f32x4){0.f, 0.f, 0.f, 0.f};

    const ushort* bp = w2 + (16 * wv + col) * 576 + g * 8;

    #pragma unroll
    for (int s = 0; s < 2; ++s) {
        bf16x8 Bs[9];
        #pragma unroll
        for (int tap = 0; tap < 9; ++tap)
            Bs[tap] = *(const bf16x8*)(bp + tap * 64 + s * 32);
        const int kgoff = (s * 4 + g) * (WW * 8);
        #pragma unroll
        for (int kw = 0; kw < 3; ++kw) {
            bf16x8 f[10];
            #pragma unroll
            for (int R = 0; R < 10; ++R)
                f[R] = *(const bf16x8*)(xg + rowbase[R] + kgoff + coloff[kw]);
            __builtin_amdgcn_sched_barrier(0);   // loads clustered before MFMAs
            #pragma unroll
            for (int Mt = 0; Mt < 8; ++Mt) {
                acc[Mt] = __builtin_amdgcn_mfma_f32_16x16x32_bf16(Bs[kw],     f[Mt],     acc[Mt], 0, 0, 0);
                acc[Mt] = __builtin_amdgcn_mfma_f32_16x16x32_bf16(Bs[3 + kw], f[Mt + 1], acc[Mt], 0, 0, 0);
                acc[Mt] = __builtin_amdgcn_mfma_f32_16x16x32_bf16(Bs[6 + kw], f[Mt + 2], acc[Mt], 0, 0, 0);
            }
        }
    }

    // ---- epilogue: D col = lane&15 = pixel col (contiguous); D row = o-quad.
    const int pcol = tj0 + col;
    const int obase = 16 * wv + 4 * g;
    float bv[4];
    #pragma unroll
    for (int reg = 0; reg < 4; ++reg) bv[reg] = bias[obase + reg];

    if (pcol < HOUT) {
        #pragma unroll
        for (int Mt = 0; Mt < 8; ++Mt) {
            const int row = ti0 + Mt;
            if (row < HOUT) {
                float* rp = out + ((size_t)(b * NCH + obase) * HOUT + row) * HOUT + pcol;
                #pragma unroll
                for (int reg = 0; reg < 4; ++reg)
                    rp[(size_t)reg * HOUT * HOUT] = acc[Mt][reg] + bv[reg];
            }
        }
    }
}

extern "C" void kernel_launch(void* const* d_in, const int* in_sizes, int n_in,
                              void* d_out, int out_size, void* d_ws, size_t ws_size,
                              hipStream_t stream) {
    const float* x       = (const float*)d_in[0];
    const float* weight  = (const float*)d_in[1];
    const float* bias    = (const float*)d_in[2];
    const int*   conn_in = (const int*)d_in[3];
    // d_in[4] = conn_out (implicit: k -> k/16)

    ushort* w2 = (ushort*)d_ws;                          // 73,728 B
    ushort* xg = (ushort*)((char*)d_ws + XG_OFF);        // 18.9 MB K-split bf16

    ksplit_cast<<<dim3(6 * HH, 4), dim3(256), 0, stream>>>(x, xg);
    build_w2<<<dim3((W2_N + 255) / 256), dim3(256), 0, stream>>>(weight, conn_in, w2);

    scm_mfma<<<dim3(1152), dim3(256), 0, stream>>>(xg, w2, bias, (float*)d_out);
}

// Round 26
// 33.782 us; speedup vs baseline: 2.0396x; 1.3400x over previous
//
#include <hip/hip_runtime.h>
#include <hip/hip_bf16.h>

#define HH 192
#define WW 192
#define HOUT 190
#define NCH 64
#define W2_N (64 * 9 * 64)

typedef __attribute__((ext_vector_type(8))) short bf16x8;
typedef __attribute__((ext_vector_type(4))) float f32x4;

static __device__ __forceinline__ ushort f2bf(float f) {
    __hip_bfloat16 h = __float2bfloat16(f);   // RNE
    return *reinterpret_cast<ushort*>(&h);
}
static __device__ __forceinline__ uint pack2bf(float lo, float hi) {
    return (uint)f2bf(lo) | ((uint)f2bf(hi) << 16);
}

// W2[o][tap][c] = sum_t (conn[o*16+t]==c) * w[(o*16+t)*9 + tap], bf16.
__global__ __launch_bounds__(256) void build_w2(const float* __restrict__ w,
                                                const int* __restrict__ conn,
                                                ushort* __restrict__ w2) {
    int idx = blockIdx.x * 256 + threadIdx.x;
    if (idx >= W2_N) return;
    int o = idx / 576, rem = idx - o * 576, tap = rem >> 6, c = rem & 63;
    float s = 0.f;
    #pragma unroll
    for (int t = 0; t < 16; ++t) {
        int k = o * 16 + t;
        if (conn[k] == c) s += w[k * 9 + tap];
    }
    w2[idx] = f2bf(s);
}

// Dense 64->64 3x3 conv via mfma_f32_16x16x32_bf16, operand-swapped
// (A = W2 -> D rows = o-quads, D lanes = contiguous pixel cols).
// R26 = R23 + register-double-buffered cluster pipeline: cluster i+1's 10
// ds_reads issue BEFORE cluster i's MFMAs; no sched_barrier in compute
// (compiler's fine-grained lgkmcnt overlaps load latency with MFMA issue).
__global__ __launch_bounds__(256, 3) void scm_mfma(
    const float* __restrict__ x,
    const ushort* __restrict__ w2,
    const float* __restrict__ bias,
    float* __restrict__ out)
{
    __shared__ ushort xt[10 * 18 * 72];   // 25,920 B

    const int tid  = threadIdx.x;
    const int lane = tid & 63;
    const int wv   = tid >> 6;
    const int col  = lane & 15;           // A-frag m (o) / B-frag n (pixel col)
    const int g    = lane >> 4;           // k-subgroup

    // Flattened grid (1152) + bijective XCD swizzle (1152 % 8 == 0).
    const int bid = blockIdx.x;
    const int lid = (bid & 7) * 144 + (bid >> 3);
    const int b      = lid / 288;
    const int tileid = lid % 288;
    const int ti0 = (tileid / 12) * 8;    // 24 row tiles
    const int tj0 = (tileid % 12) * 16;   // 12 col tiles

    // ---- staging: spatial-lane gather, wave-sliced channels, packed b32 writes.
    {
        const int srr  = lane / 18;       // 0..2 (lanes 54..63: writes masked)
        const int scol = lane - srr * 18; // 0..17
        const bool act = lane < 54;
        int gc = tj0 + scol; if (gc > 191) gc = 191;
        int gr0 = ti0 + srr;     if (gr0 > 191) gr0 = 191;
        int gr1 = ti0 + srr + 3; if (gr1 > 191) gr1 = 191;
        int gr2 = ti0 + srr + 6; if (gr2 > 191) gr2 = 191;
        int gr3 = ti0 + srr + 9; if (gr3 > 191) gr3 = 191;

        #pragma unroll
        for (int pass = 0; pass < 2; ++pass) {
            float v[8][4];
            #pragma unroll
            for (int pj = 0; pj < 8; ++pj) {
                const int c = wv * 16 + pass * 8 + pj;
                const float* xc = x + ((size_t)(b * NCH + c)) * (HH * WW);
                v[pj][0] = xc[gr0 * WW + gc];
                v[pj][1] = xc[gr1 * WW + gc];
                v[pj][2] = xc[gr2 * WW + gc];
                v[pj][3] = xc[gr3 * WW + gc];
            }
            __builtin_amdgcn_sched_barrier(0);   // all 32 loads in flight first
            if (act) {
                #pragma unroll
                for (int pp = 0; pp < 4; ++pp) {
                    const int c = wv * 16 + pass * 8 + 2 * pp;   // even
                    uint k0 = pack2bf(v[2 * pp][0], v[2 * pp + 1][0]);
                    uint k1 = pack2bf(v[2 * pp][1], v[2 * pp + 1][1]);
                    uint k2 = pack2bf(v[2 * pp][2], v[2 * pp + 1][2]);
                    uint k3 = pack2bf(v[2 * pp][3], v[2 * pp + 1][3]);
                    *(uint*)&xt[((srr    ) * 18 + scol) * 72 + c] = k0;
                    *(uint*)&xt[((srr + 3) * 18 + scol) * 72 + c] = k1;
                    *(uint*)&xt[((srr + 6) * 18 + scol) * 72 + c] = k2;
                    if (srr == 0)
                        *(uint*)&xt[(9 * 18 + scol) * 72 + c] = k3;
                }
            }
        }
    }
    __syncthreads();

    // ---- compute (operand-swapped), register-double-buffered pipeline.
    f32x4 acc[8];
    #pragma unroll
    for (int i = 0; i < 8; ++i) acc[i] = (f32x4){0.f, 0.f, 0.f, 0.f};

    const ushort* ap0 = &xt[col * 72 + g * 8];
    const ushort* bp  = w2 + (16 * wv + col) * 576 + g * 8;

    bf16x8 fA[10], fB[10];
    bf16x8 Bs[9];

#define LOADB(s) do {                                                          \
        _Pragma("unroll")                                                      \
        for (int _tap = 0; _tap < 9; ++_tap)                                   \
            Bs[_tap] = *(const bf16x8*)(bp + _tap * 64 + (s) * 32);            \
    } while (0)

#define LOADF(F, s, kw) do {                                                   \
        _Pragma("unroll")                                                      \
        for (int _R = 0; _R < 10; ++_R)                                        \
            F[_R] = *(const bf16x8*)(ap0 + (_R * 18 + (kw)) * 72 + (s) * 32);  \
    } while (0)

#define MFMA24(F, kw) do {                                                     \
        _Pragma("unroll")                                                      \
        for (int _Mt = 0; _Mt < 8; ++_Mt) {                                    \
            acc[_Mt] = __builtin_amdgcn_mfma_f32_16x16x32_bf16(Bs[kw],     F[_Mt],     acc[_Mt], 0, 0, 0); \
            acc[_Mt] = __builtin_amdgcn_mfma_f32_16x16x32_bf16(Bs[3+(kw)], F[_Mt + 1], acc[_Mt], 0, 0, 0); \
            acc[_Mt] = __builtin_amdgcn_mfma_f32_16x16x32_bf16(Bs[6+(kw)], F[_Mt + 2], acc[_Mt], 0, 0, 0); \
        }                                                                      \
    } while (0)

    LOADB(0);
    LOADF(fA, 0, 0);
    LOADF(fB, 0, 1);  MFMA24(fA, 0);     // fB's reads fly under fA's MFMAs
    LOADF(fA, 0, 2);  MFMA24(fB, 1);
    LOADF(fB, 1, 0);  MFMA24(fA, 2);
    LOADB(1);                             // Bs for s=1 (fB cluster waits on lgkm anyway)
    LOADF(fA, 1, 1);  MFMA24(fB, 0);
    LOADF(fB, 1, 2);  MFMA24(fA, 1);
    MFMA24(fB, 2);

#undef LOADB
#undef LOADF
#undef MFMA24

    // ---- epilogue: D col = lane&15 = pixel col (contiguous); D row = o-quad.
    const int pcol = tj0 + col;
    const int obase = 16 * wv + 4 * g;
    float bv[4];
    #pragma unroll
    for (int reg = 0; reg < 4; ++reg) bv[reg] = bias[obase + reg];

    if (pcol < HOUT) {
        #pragma unroll
        for (int Mt = 0; Mt < 8; ++Mt) {
            const int row = ti0 + Mt;
            if (row < HOUT) {
                float* rp = out + ((size_t)(b * NCH + obase) * HOUT + row) * HOUT + pcol;
                #pragma unroll
                for (int reg = 0; reg < 4; ++reg)
                    rp[(size_t)reg * HOUT * HOUT] = acc[Mt][reg] + bv[reg];
            }
        }
    }
}

extern "C" void kernel_launch(void* const* d_in, const int* in_sizes, int n_in,
                              void* d_out, int out_size, void* d_ws, size_t ws_size,
                              hipStream_t stream) {
    const float* x       = (const float*)d_in[0];
    const float* weight  = (const float*)d_in[1];
    const float* bias    = (const float*)d_in[2];
    const int*   conn_in = (const int*)d_in[3];
    // d_in[4] = conn_out (implicit: k -> k/16)

    ushort* w2 = (ushort*)d_ws;   // 73,728 B

    build_w2<<<dim3((W2_N + 255) / 256), dim3(256), 0, stream>>>(weight, conn_in, w2);

    scm_mfma<<<dim3(1152), dim3(256), 0, stream>>>(x, w2, bias, (float*)d_out);
}